// Round 6
// baseline (166.910 us; speedup 1.0000x reference)
//
#include <hip/hip_runtime.h>
#include <math.h>

#ifndef __has_builtin
#define __has_builtin(x) 0
#endif

__device__ __forceinline__ float fast_exp2(float v) {
#if __has_builtin(__builtin_amdgcn_exp2f)
    return __builtin_amdgcn_exp2f(v);   // v_exp_f32 (base-2), ~1 ulp
#else
    return exp2f(v);
#endif
}

constexpr int R  = 20;  // reads per site
constexpr int C  = 32;  // channels
constexpr int B  = 32;  // bins
constexpr int BC = 8;   // bin chunk (stores spread in 4 bursts of 8)

// One thread per (site, channel); lane = channel -> every load/store instr is
// two 128B-contiguous segments per wave64 (2 sites). Fully coalesced; all
// immediate offsets fit the 13-bit signed global imm.
//
// KDE factorization (bin centers b/31, sigma^2 = 0.01):
//   exp(-50(x - b/31)^2) = 2^{-Kx^2} * (2^{A2 x + B0})^b * 2^{-(K/961) b(b-1)}
//   K = 50*log2(e), A2 = 2K/31, B0 = -K/961.
// Data-independent factor folded into per-bin store constants.
//
// CHUNKED BINS-OUTER: per-read running power P[r] (=2^{-Kx^2} * m^bin) and
// step M[r] persist in regs across 4 chunks of 8 bins; each chunk accumulates
// acc[8] and stores immediately. vs R3/R5's acc[32]: store traffic is spread
// through the wave lifetime, live set drops to ~55 regs -> launch_bounds
// (256,7) = 73-reg budget, 7 waves/SIMD (R4's spill trap was acc-free
// bins-outer at a 64-reg cap; acc[8] keeps us clear of the 73 cap).
__global__ __launch_bounds__(256, 7) void kde_kernel(const float* __restrict__ x,
                                                     float* __restrict__ out,
                                                     int nsites) {
    int t = blockIdx.x * blockDim.x + threadIdx.x;
    int c = t & (C - 1);
    int n = t >> 5;
    if (n >= nsites) return;

    const float K  = 72.13475204444817f;    // 50 * log2(e)
    const float A2 = 4.6538549706095594f;   // 2K/31
    const float B0 = -0.07506217694531545f; // -K/961

    const float* xp = x + (size_t)n * (R * C) + c;

    // per-read running power / step multiplier (loads non-temporal; compiler
    // batches the 20 loads ahead of the exp2 chain)
    float Pv[R], M[R];
#pragma unroll
    for (int r = 0; r < R; ++r) {
        float v = __builtin_nontemporal_load(&xp[(size_t)r * C]);
        Pv[r] = fast_exp2(v * v * -K);        // 2^{-K x^2}
        M[r]  = fast_exp2(fmaf(v, A2, B0));   // 2^{A2 x + B0}
    }

    float* op = out + (size_t)n * (B * C) + c;
#pragma unroll
    for (int base = 0; base < B; base += BC) {
        float acc[BC];
#pragma unroll
        for (int b = 0; b < BC; ++b) acc[b] = 0.0f;

#pragma unroll
        for (int r = 0; r < R; ++r) {
            float p = Pv[r];
            float m = M[r];
#pragma unroll
            for (int b = 0; b < BC; ++b) {
                acc[b] += p;       // p == 2^{-Kx^2} * m^(base+b)
                p *= m;
            }
            Pv[r] = p;             // carry power into next chunk
        }

#pragma unroll
        for (int b = 0; b < BC; ++b) {
            const int bb = base + b;   // compile-time after unroll
            const float cb = (float)(0.19947114020071635 *
                                     exp2(-0.07506217694531545 * (double)(bb * (bb - 1))));
            __builtin_nontemporal_store(acc[b] * cb, &op[(size_t)bb * C]);
        }
    }
}

extern "C" void kernel_launch(void* const* d_in, const int* in_sizes, int n_in,
                              void* d_out, int out_size, void* d_ws, size_t ws_size,
                              hipStream_t stream) {
    const float* x = (const float*)d_in[0];
    float* out = (float*)d_out;
    int nsites = in_sizes[0] / (R * C);          // 131072
    int total = nsites * C;                      // one thread per (site, channel)
    int block = 256;
    int grid = (total + block - 1) / block;
    hipLaunchKernelGGL(kde_kernel, dim3(grid), dim3(block), 0, stream, x, out, nsites);
}